// Round 8
// baseline (401.303 us; speedup 1.0000x reference)
//
#include <hip/hip_runtime.h>
#include <hip/hip_bf16.h>
#include <hip/hip_cooperative_groups.h>

namespace cg = cooperative_groups;

// Problem constants
#define BATCH 64
#define NATOM 120
#define NNB 10
#define NBOND 250
#define AFDIM 82
#define BFDIM 6
#define HREAL 300
#define HP 320            // padded H (bf16 activation row stride); pad cols hold exact 0
#define NCT32 10          // 10 col-tiles of 32 -> 320
#define MA (BATCH*NATOM)  // 7680
#define MB (BATCH*NBOND)  // 16000

typedef short short8 __attribute__((ext_vector_type(8)));   // 8 bf16 (4 VGPRs)
typedef float f32x16 __attribute__((ext_vector_type(16)));  // 32x32 MFMA accumulator
typedef unsigned int u32;
typedef u32 u32x2 __attribute__((ext_vector_type(2)));
typedef unsigned short u16;

__device__ __forceinline__ float bflo(u32 v) { return __builtin_bit_cast(float, v << 16); }
__device__ __forceinline__ float bfhi(u32 v) { return __builtin_bit_cast(float, v & 0xffff0000u); }
__device__ __forceinline__ u16 f2bf(float f) {
    __hip_bfloat16 h = __float2bfloat16(f);
    return __builtin_bit_cast(u16, h);
}
__device__ __forceinline__ int imin(int a, int b) { return a < b ? a : b; }

// ================= arg block =================
struct PackJob { const float* W; short8* dst; int Kreal, KT, KTfull, ktOff, blk0; };
struct MegaArgs {
    const float *a1src, *bsrc;
    __hip_bfloat16 *A1b, *bondb;
    const int *mn, *agp, *bgp;
    u32* pk;
    PackJob j[8];
    const short8 *pW1, *pWbd, *pWnei, *pWga, *pWfd;
    const float *b_gn, *b_ga;
    __hip_bfloat16 *af0, *af1, *neib, *bondgc, *bnb;
    const int* maska;
    float* out;
};

// ---- prep work chunks (identical math to R7 prep_all; bid = chunk index) ----
#define CONV1_BLKS 2880   // MA*96/256
#define CONV2_BLKS 2000   // MB*32/256
#define PACK_BASE  (CONV1_BLKS + CONV2_BLKS)
#define PACK_BLKS  275
#define PK_BASE    (PACK_BASE + PACK_BLKS)
#define PK_BLKS    300    // MA*NNB/256
#define PREP_BLKS  (PK_BASE + PK_BLKS)   // 5455

__device__ void prep_chunk(const MegaArgs& A, int bid, int tid) {
    if (bid < CONV1_BLKS) {
        int id = bid * 256 + tid;                 // exact multiple
        int r = id / 96, c = id - r * 96;
        float f = (c < AFDIM) ? A.a1src[(size_t)r * AFDIM + c] : 0.f;
        A.A1b[id] = __float2bfloat16(f);
    } else if (bid < PACK_BASE) {
        int id = (bid - CONV1_BLKS) * 256 + tid;  // exact multiple
        int r = id >> 5, c = id & 31;
        float f = (c < BFDIM) ? A.bsrc[(size_t)r * BFDIM + c] : 0.f;
        A.bondb[id] = __float2bfloat16(f);
    } else if (bid < PK_BASE) {
        const int pid = bid - PACK_BASE;
        int ji = 0;
#pragma unroll
        for (int i = 1; i < 8; ++i) if (pid >= A.j[i].blk0) ji = i;
        const PackJob J = A.j[ji];
        int id = (pid - J.blk0) * 256 + tid;
        int n = NCT32 * J.KT * 64;
        if (id >= n) return;
        int lane = id & 63;
        int kt = (id >> 6) % J.KT;
        int ct = id / (J.KT * 64);
        int col = ct * 32 + (lane & 31);
        int kbase = kt * 16 + (lane >> 5) * 8;
        short8 v;
#pragma unroll
        for (int jj = 0; jj < 8; ++jj) {
            int k = kbase + jj;
            float f = (k < J.Kreal && col < HREAL) ? J.W[(size_t)k * HREAL + col] : 0.f;
            v[jj] = (short)f2bf(f);
        }
        J.dst[(size_t)(ct * J.KTfull + J.ktOff + kt) * 64 + lane] = v;
    } else {
        int id = (bid - PK_BASE) * 256 + tid;     // exact multiple (76800)
        u32 w = 0;
        if (A.mn[id]) w = 0x80000000u | ((u32)A.agp[id] << 16) | (u32)A.bgp[id];
        A.pk[id] = w;
    }
}

// ================= generic 4-wave MFMA GEMM tile (W staged in LDS) =================
// 128 rows x 2 col-tiles. A = [A1|A2] split at kt==KT1 (row strides KT1*16 / (KT-KT1)*16).
// ct<NCT32 -> out0, else out1 (col-HP). bias applied to out0 path only.
template<int KT, int KT1, bool RELU>
__device__ __forceinline__ void gemm_tile(short8* Wl, int bx, int by, int tid,
    const __hip_bfloat16* __restrict__ A1,
    const __hip_bfloat16* __restrict__ A2,
    const short8* __restrict__ Wp,
    const float* __restrict__ bias0,
    __hip_bfloat16* __restrict__ out0,
    __hip_bfloat16* __restrict__ out1) {
    const int lane = tid & 63;
    const int wv   = tid >> 6;
    const int m0   = bx * 128 + wv * 32;
    const int ct0  = by * 2;
    const int r1   = m0 + (lane & 31);
    const int koff = (lane >> 5) * 8;

    constexpr int S1  = KT1 * 16;
    constexpr int S2  = (KT - KT1) * 16;
    constexpr int CH  = (KT >= 10) ? 10 : KT;
    constexpr int NCH = KT / CH;
    constexpr int NW  = 2 * KT * 64;           // 256-divisible for KT in {2,6,40}

    {
        const short8* wsrc = Wp + (size_t)ct0 * KT * 64;
#pragma unroll
        for (int i = 0; i < NW / 256; ++i) Wl[i * 256 + tid] = wsrc[i * 256 + tid];
    }
    __syncthreads();

    f32x16 acc[2];
#pragma unroll
    for (int r = 0; r < 16; ++r) { acc[0][r] = 0.f; acc[1][r] = 0.f; }

    const short8* w0 = Wl + lane;
    const short8* w1 = Wl + KT * 64 + lane;

#pragma unroll
    for (int ch = 0; ch < NCH; ++ch) {
        short8 a[CH];
#pragma unroll
        for (int kt = 0; kt < CH; ++kt) {
            const int g = ch * CH + kt;
            if (g < KT1)
                a[kt] = *reinterpret_cast<const short8*>(A1 + (size_t)r1 * S1 + g * 16 + koff);
            else
                a[kt] = *reinterpret_cast<const short8*>(A2 + (size_t)r1 * S2 + (g - KT1) * 16 + koff);
        }
#pragma unroll
        for (int kt = 0; kt < CH; ++kt) {
            const int g = ch * CH + kt;
            acc[0] = __builtin_amdgcn_mfma_f32_32x32x16_bf16(a[kt], w0[g * 64], acc[0], 0, 0, 0);
            acc[1] = __builtin_amdgcn_mfma_f32_32x32x16_bf16(a[kt], w1[g * 64], acc[1], 0, 0, 0);
        }
    }

#pragma unroll
    for (int c = 0; c < 2; ++c) {
        const int ct = ct0 + c;
        const bool second = (ct >= NCT32);
        const int colb = second ? ct * 32 - HP : ct * 32;
        const int col = colb + (lane & 31);
        __hip_bfloat16* op = second ? out1 : out0;
        const float bb = (!second && bias0 && col < HREAL) ? bias0[col] : 0.f;
#pragma unroll
        for (int r = 0; r < 16; ++r) {
            const int row = m0 + (r & 3) + 8 * (r >> 2) + 4 * (lane >> 5);
            float v = acc[c][r] + bb;
            if (RELU) v = fmaxf(v, 0.f);
            op[(size_t)row * HP + col] = __float2bfloat16(v);
        }
    }
}

// ================= fused nu-GEMM + gather tile (per batch, 32-col tile) =================
__device__ void nu_tile(char* smraw,
                        const __hip_bfloat16* __restrict__ af,
                        const short8* __restrict__ pWnei,
                        const u32* __restrict__ bondgc,
                        const u32* __restrict__ pk,
                        u32* __restrict__ nei,
                        int b, int ct, int tid) {
    short8* WL = (short8*)smraw;                       // [20*64] 20480 B
    u16*    TL = (u16*)(smraw + 20480);                // [120][32]
    u16*    BLh = (u16*)(smraw + 20480 + 7680);        // [250][32]
    u32*    PL = (u32*)(smraw + 20480 + 7680 + 16000); // [1200]
    u32*    BL = (u32*)BLh;

    {
        const short8* wsrc = pWnei + (size_t)ct * 20 * 64;
#pragma unroll
        for (int i = 0; i < 5; ++i) WL[i * 256 + tid] = wsrc[i * 256 + tid];
    }
    for (int i = tid; i < 2000; i += 256) {
        int r = i >> 3, w = i & 7;
        *reinterpret_cast<u32x2*>(&BL[r * 16 + 2 * w]) =
            *reinterpret_cast<const u32x2*>(bondgc + (size_t)(b * NBOND + r) * (HP / 2) + ct * 16 + 2 * w);
    }
    for (int i = tid; i < NATOM * NNB; i += 256) PL[i] = pk[b * NATOM * NNB + i];
    __syncthreads();

    {
        const int lane = tid & 63;
        const int wv   = tid >> 6;
        const int r1   = imin(wv * 32 + (lane & 31), NATOM - 1);
        const int koff = (lane >> 5) * 8;
        const __hip_bfloat16* arow = af + (size_t)(b * NATOM + r1) * HP + koff;
        f32x16 acc;
#pragma unroll
        for (int r = 0; r < 16; ++r) acc[r] = 0.f;
        const short8* w0 = WL + lane;
#pragma unroll
        for (int ch = 0; ch < 2; ++ch) {
            short8 a[10];
#pragma unroll
            for (int kt = 0; kt < 10; ++kt)
                a[kt] = *reinterpret_cast<const short8*>(arow + (ch * 10 + kt) * 16);
#pragma unroll
            for (int kt = 0; kt < 10; ++kt)
                acc = __builtin_amdgcn_mfma_f32_32x32x16_bf16(a[kt], w0[(ch * 10 + kt) * 64], acc, 0, 0, 0);
        }
        const int col = lane & 31;
#pragma unroll
        for (int r = 0; r < 16; ++r) {
            const int row = wv * 32 + (r & 3) + 8 * (r >> 2) + 4 * (lane >> 5);
            if (row < NATOM) TL[row * 32 + col] = f2bf(acc[r]);
        }
    }
    __syncthreads();

    for (int i = tid; i < NATOM * 16; i += 256) {
        const int row = i >> 4, cp = i & 15;
        float lo = 0.f, hi = 0.f;
#pragma unroll
        for (int j = 0; j < NNB; ++j) {
            const u32 w = PL[row * NNB + j];
            if ((int)w < 0) {
                const int a  = (w >> 16) & 0xff;
                const int bo = w & 0xffff;
                const u32 ta = *reinterpret_cast<const u32*>(&TL[a * 32 + 2 * cp]);
                const u32 tb = BL[bo * 16 + cp];
                lo += fmaxf(bflo(ta) + bflo(tb), 0.f);
                hi += fmaxf(bfhi(ta) + bfhi(tb), 0.f);
            }
        }
        nei[(size_t)(b * NATOM + row) * (HP / 2) + ct * 16 + cp] =
            (u32)f2bf(lo) | ((u32)f2bf(hi) << 16);
    }
}

// ================= fused final GEMM + product tile (per batch, 32-col tile) =================
__device__ void fin_tile(char* smraw,
                         const __hip_bfloat16* __restrict__ af,
                         const short8* __restrict__ pWfd,
                         const u32* __restrict__ bnb,
                         const u32* __restrict__ pk,
                         const int* __restrict__ maska,
                         float* __restrict__ out,
                         int b, int ct, int tid) {
    short8* WL = (short8*)smraw;                              // [2*20*64] 40960 B
    u16*    SL = (u16*)(smraw + 40960);                       // selfF [120][32]
    u16*    AL = (u16*)(smraw + 40960 + 7680);                // A2f   [120][32]
    u16*    BLh = (u16*)(smraw + 40960 + 2 * 7680);           // bnb   [250][32]
    u32*    PL = (u32*)(smraw + 40960 + 2 * 7680 + 16000);    // [1200]
    u32*    ML = PL + 1200;                                   // [120]
    u32*    BL = (u32*)BLh;

    {
        const short8* w2  = pWfd + (size_t)ct * 20 * 64;
        const short8* w2a = pWfd + (size_t)(NCT32 + ct) * 20 * 64;
#pragma unroll
        for (int i = 0; i < 5; ++i) {
            WL[i * 256 + tid]        = w2[i * 256 + tid];
            WL[1280 + i * 256 + tid] = w2a[i * 256 + tid];
        }
    }
    for (int i = tid; i < 2000; i += 256) {
        int r = i >> 3, w = i & 7;
        *reinterpret_cast<u32x2*>(&BL[r * 16 + 2 * w]) =
            *reinterpret_cast<const u32x2*>(bnb + (size_t)(b * NBOND + r) * (HP / 2) + ct * 16 + 2 * w);
    }
    for (int i = tid; i < NATOM * NNB; i += 256) PL[i] = pk[b * NATOM * NNB + i];
    for (int i = tid; i < NATOM; i += 256) ML[i] = (u32)(maska[b * NATOM + i] != 0);
    __syncthreads();

    {
        const int lane = tid & 63;
        const int wv   = tid >> 6;
        const int r1   = imin(wv * 32 + (lane & 31), NATOM - 1);
        const int koff = (lane >> 5) * 8;
        const __hip_bfloat16* arow = af + (size_t)(b * NATOM + r1) * HP + koff;
        f32x16 acc0, acc1;
#pragma unroll
        for (int r = 0; r < 16; ++r) { acc0[r] = 0.f; acc1[r] = 0.f; }
        const short8* w0 = WL + lane;
        const short8* w1 = WL + 1280 + lane;
#pragma unroll
        for (int ch = 0; ch < 2; ++ch) {
            short8 a[10];
#pragma unroll
            for (int kt = 0; kt < 10; ++kt)
                a[kt] = *reinterpret_cast<const short8*>(arow + (ch * 10 + kt) * 16);
#pragma unroll
            for (int kt = 0; kt < 10; ++kt) {
                acc0 = __builtin_amdgcn_mfma_f32_32x32x16_bf16(a[kt], w0[(ch * 10 + kt) * 64], acc0, 0, 0, 0);
                acc1 = __builtin_amdgcn_mfma_f32_32x32x16_bf16(a[kt], w1[(ch * 10 + kt) * 64], acc1, 0, 0, 0);
            }
        }
        const int col = lane & 31;
#pragma unroll
        for (int r = 0; r < 16; ++r) {
            const int row = wv * 32 + (r & 3) + 8 * (r >> 2) + 4 * (lane >> 5);
            if (row < NATOM) {
                SL[row * 32 + col] = f2bf(acc0[r]);
                AL[row * 32 + col] = f2bf(acc1[r]);
            }
        }
    }
    __syncthreads();

    for (int i = tid; i < NATOM * 16; i += 256) {
        const int row = i >> 4, cp = i & 15;
        const int c = ct * 32 + 2 * cp;
        if (c >= HREAL) continue;
        float lo = 0.f, hi = 0.f;
#pragma unroll
        for (int j = 0; j < NNB; ++j) {
            const u32 w = PL[row * NNB + j];
            if ((int)w < 0) {
                const int a  = (w >> 16) & 0xff;
                const int bo = w & 0xffff;
                const u32 va = *reinterpret_cast<const u32*>(&AL[a * 32 + 2 * cp]);
                const u32 vb = BL[bo * 16 + cp];
                lo += bflo(va) * bflo(vb);
                hi += bfhi(va) * bfhi(vb);
            }
        }
        float2 r2;
        r2.x = 0.f; r2.y = 0.f;
        if (ML[row]) {
            const u32 s = *reinterpret_cast<const u32*>(&SL[row * 32 + 2 * cp]);
            r2.x = bflo(s) * lo;
            r2.y = bfhi(s) * hi;
        }
        *reinterpret_cast<float2*>(out + (size_t)(b * NATOM + row) * HREAL + c) = r2;
    }
}

// ================= the cooperative mega-kernel: all 7 stages, 6 grid syncs =================
#define MEGA_LDS (2 * 40 * 64 * 16)    // 81920 B (bot panel; max over phases) -> 2 blocks/CU
#define FC1_TILES  (MA/128 * 5)        // 300
#define BOND_TILES (MB/128 * 10)       // 1250
#define BOT_TILES  (MA/128 * 5)        // 300
#define NUG_TILES  (BATCH * NCT32)     // 640

__global__ __launch_bounds__(256, 2)
void mega(MegaArgs A) {
    extern __shared__ char sm[];
    const int tid = threadIdx.x;
    cg::grid_group grid = cg::this_grid();

    // ---- P0: prep (convs + weight packs + pk) ----
    for (int c = blockIdx.x; c < PREP_BLKS; c += gridDim.x) prep_chunk(A, c, tid);
    grid.sync();

    // ---- P1: input GEMMs (fc1 + bond dual) ----
    for (int t = blockIdx.x; t < FC1_TILES + BOND_TILES; t += gridDim.x) {
        __syncthreads();   // previous tile's LDS reads complete
        if (t < FC1_TILES)
            gemm_tile<6, 6, true>((short8*)sm, t % (MA/128), t / (MA/128), tid,
                                  A.A1b, A.A1b, A.pW1, nullptr, A.af0, nullptr);
        else {
            const int u = t - FC1_TILES;
            gemm_tile<2, 2, false>((short8*)sm, u % (MB/128), u / (MB/128), tid,
                                   A.bondb, A.bondb, A.pWbd, A.b_gn, A.bondgc, A.bnb);
        }
    }
    grid.sync();

    // ---- graph-conv iterations ----
    const __hip_bfloat16* af = A.af0;
    __hip_bfloat16* afn = A.af1;
    for (int it = 0; it < 2; ++it) {
        for (int t = blockIdx.x; t < NUG_TILES; t += gridDim.x) {
            __syncthreads();
            nu_tile(sm, af, A.pWnei, (const u32*)A.bondgc, A.pk, (u32*)A.neib,
                    t / NCT32, t % NCT32, tid);
        }
        grid.sync();
        for (int t = blockIdx.x; t < BOT_TILES; t += gridDim.x) {
            __syncthreads();
            gemm_tile<40, 20, true>((short8*)sm, t % (MA/128), t / (MA/128), tid,
                                    af, A.neib, A.pWga, A.b_ga, afn, nullptr);
        }
        grid.sync();
        const __hip_bfloat16* tmp = afn; afn = (__hip_bfloat16*)af; af = tmp;
    }

    // ---- final fused layer ----
    for (int t = blockIdx.x; t < NUG_TILES; t += gridDim.x) {
        __syncthreads();
        fin_tile(sm, af, A.pWfd, (const u32*)A.bnb, A.pk, A.maska, A.out,
                 t / NCT32, t % NCT32, tid);
    }
}

extern "C" void kernel_launch(void* const* d_in, const int* in_sizes, int n_in,
                              void* d_out, int out_size, void* d_ws, size_t ws_size,
                              hipStream_t stream) {
    const float* A1        = (const float*)d_in[0];
    const float* bond      = (const float*)d_in[1];
    const int*   ag        = (const int*)d_in[2];
    const int*   bg        = (const int*)d_in[3];
    const int*   maskn     = (const int*)d_in[6];
    const int*   maska     = (const int*)d_in[7];
    const float* W_fc1     = (const float*)d_in[8];
    const float* W_gc_nei  = (const float*)d_in[9];
    const float* b_gc_nei  = (const float*)d_in[10];
    const float* W_gc_atom = (const float*)d_in[11];
    const float* b_gc_atom = (const float*)d_in[12];
    const float* W_fc2a    = (const float*)d_in[13];
    const float* W_fc2b    = (const float*)d_in[14];
    const float* W_fc2     = (const float*)d_in[15];
    float* out = (float*)d_out;

    // ---- workspace carve-up ----
    char* p = (char*)d_ws;
    auto alloc = [&](size_t bytes) { char* r = p; p += (bytes + 63) & ~(size_t)63; return r; };
    __hip_bfloat16* A1b    = (__hip_bfloat16*)alloc((size_t)MA * 96 * 2);
    __hip_bfloat16* bondb  = (__hip_bfloat16*)alloc((size_t)MB * 32 * 2);
    __hip_bfloat16* af0    = (__hip_bfloat16*)alloc((size_t)MA * HP * 2);
    __hip_bfloat16* af1    = (__hip_bfloat16*)alloc((size_t)MA * HP * 2);
    __hip_bfloat16* neib   = (__hip_bfloat16*)alloc((size_t)MA * HP * 2);
    __hip_bfloat16* bondgc = (__hip_bfloat16*)alloc((size_t)MB * HP * 2);
    __hip_bfloat16* bnb    = (__hip_bfloat16*)alloc((size_t)MB * HP * 2);
    u32*            pk     = (u32*)alloc((size_t)MA * NNB * 4);
    short8* pW1  = (short8*)alloc((size_t)NCT32 * 6  * 64 * 16);        // fc1          K=96
    short8* pWnei= (short8*)alloc((size_t)NCT32 * 20 * 64 * 16);        // gc_nei[:H]   K=320
    short8* pWga = (short8*)alloc((size_t)NCT32 * 40 * 64 * 16);        // gc_atom cat  K=640
    short8* pWbd = (short8*)alloc((size_t)2 * NCT32 * 2 * 64 * 16);     // bond dual    K=32, 20 ct
    short8* pWfd = (short8*)alloc((size_t)2 * NCT32 * 20 * 64 * 16);    // fc2 | fc2a   K=320, 20 ct

    // ---- args ----
    MegaArgs ma;
    ma.a1src = A1;   ma.A1b   = A1b;
    ma.bsrc  = bond; ma.bondb = bondb;
    ma.mn = maskn; ma.agp = ag; ma.bgp = bg; ma.pk = pk;
    //          W                                  dst                          Kreal  KT KTf off blk0
    ma.j[0] = { W_fc1,                             pW1,                         AFDIM, 6,  6,  0,   0 };
    ma.j[1] = { W_gc_nei,                          pWnei,                       HREAL, 20, 20, 0,  15 };
    ma.j[2] = { W_gc_atom,                         pWga,                        HREAL, 20, 40, 0,  65 };
    ma.j[3] = { W_gc_atom + (size_t)HREAL * HREAL, pWga,                        HREAL, 20, 40, 20, 115 };
    ma.j[4] = { W_gc_nei + (size_t)HREAL * HREAL,  pWbd,                        BFDIM, 2,  2,  0, 165 };
    ma.j[5] = { W_fc2b,                            pWbd + (size_t)NCT32*2*64,   BFDIM, 2,  2,  0, 170 };
    ma.j[6] = { W_fc2,                             pWfd,                        HREAL, 20, 20, 0, 175 };
    ma.j[7] = { W_fc2a,                            pWfd + (size_t)NCT32*20*64,  HREAL, 20, 20, 0, 225 };
    ma.pW1 = pW1; ma.pWbd = pWbd; ma.pWnei = pWnei; ma.pWga = pWga; ma.pWfd = pWfd;
    ma.b_gn = b_gc_nei; ma.b_ga = b_gc_atom;
    ma.af0 = af0; ma.af1 = af1; ma.neib = neib; ma.bondgc = bondgc; ma.bnb = bnb;
    ma.maska = maska; ma.out = out;

    // ---- one cooperative dispatch: resident grid, phases via grid.sync ----
    static int grid_blocks = 0;
    if (!grid_blocks) {
        hipFuncSetAttribute((const void*)mega, hipFuncAttributeMaxDynamicSharedMemorySize, MEGA_LDS);
        int maxb = 0;
        hipOccupancyMaxActiveBlocksPerMultiprocessor(&maxb, (const void*)mega, 256, MEGA_LDS);
        if (maxb < 1) maxb = 1;
        grid_blocks = 256 * maxb;          // 256 CUs
        if (grid_blocks > 512) grid_blocks = 512;
    }
    void* kargs[] = { &ma };
    hipLaunchCooperativeKernel((const void*)mega, dim3(grid_blocks), dim3(256),
                               kargs, MEGA_LDS, stream);
}

// Round 9
// 138.249 us; speedup vs baseline: 2.9028x; 2.9028x over previous
//
#include <hip/hip_runtime.h>
#include <hip/hip_bf16.h>

// Problem constants
#define BATCH 64
#define NATOM 120
#define NNB 10
#define NBOND 250
#define AFDIM 82
#define BFDIM 6
#define HREAL 300
#define HP 320            // padded H (bf16 activation row stride); pad cols hold exact 0
#define NCT32 10          // 10 col-tiles of 32 -> 320
#define MA (BATCH*NATOM)  // 7680
#define MB (BATCH*NBOND)  // 16000

typedef short short8 __attribute__((ext_vector_type(8)));   // 8 bf16 (4 VGPRs)
typedef float f32x16 __attribute__((ext_vector_type(16)));  // 32x32 MFMA accumulator
typedef unsigned int u32;
typedef u32 u32x2 __attribute__((ext_vector_type(2)));
typedef unsigned short u16;

__device__ __forceinline__ float bflo(u32 v) { return __builtin_bit_cast(float, v << 16); }
__device__ __forceinline__ float bfhi(u32 v) { return __builtin_bit_cast(float, v & 0xffff0000u); }
__device__ __forceinline__ u16 f2bf(float f) {
    __hip_bfloat16 h = __float2bfloat16(f);
    return __builtin_bit_cast(u16, h);
}
__device__ __forceinline__ int imin(int a, int b) { return a < b ? a : b; }

// ================= prep: convs + weight packs + packed nbr table in ONE launch =================
struct PackJob { const float* W; short8* dst; int Kreal, KT, KTfull, ktOff, blk0; };
struct Prep {
    const float* a1src; __hip_bfloat16* a1dst;   // [MA][82] -> [MA][96]
    const float* bsrc;  __hip_bfloat16* bdst;    // [MB][6]  -> [MB][32]
    const int *mn, *agp, *bgp; u32* pk;          // packed nbr table [MA*NNB]
    PackJob j[8];
};

#define CONV1_BLKS 2880   // MA*96/256
#define CONV2_BLKS 2000   // MB*32/256
#define PACK_BASE  (CONV1_BLKS + CONV2_BLKS)
#define PACK_BLKS  275
#define PK_BASE    (PACK_BASE + PACK_BLKS)
#define PK_BLKS    300    // MA*NNB/256 = 76800/256
#define PREP_BLKS  (PK_BASE + PK_BLKS)   // 5455

__global__ __launch_bounds__(256) void prep_all(Prep cfg) {
    const int bid = blockIdx.x;
    const int tid = threadIdx.x;
    if (bid < CONV1_BLKS) {
        int id = bid * 256 + tid;                 // exact multiple
        int r = id / 96, c = id - r * 96;
        float f = (c < AFDIM) ? cfg.a1src[(size_t)r * AFDIM + c] : 0.f;
        cfg.a1dst[id] = __float2bfloat16(f);
    } else if (bid < PACK_BASE) {
        int id = (bid - CONV1_BLKS) * 256 + tid;  // exact multiple
        int r = id >> 5, c = id & 31;
        float f = (c < BFDIM) ? cfg.bsrc[(size_t)r * BFDIM + c] : 0.f;
        cfg.bdst[id] = __float2bfloat16(f);
    } else if (bid < PK_BASE) {
        const int pid = bid - PACK_BASE;
        int ji = 0;
#pragma unroll
        for (int i = 1; i < 8; ++i) if (pid >= cfg.j[i].blk0) ji = i;
        const PackJob J = cfg.j[ji];
        int id = (pid - J.blk0) * 256 + tid;
        int n = NCT32 * J.KT * 64;
        if (id >= n) return;
        int lane = id & 63;
        int kt = (id >> 6) % J.KT;
        int ct = id / (J.KT * 64);
        int col = ct * 32 + (lane & 31);
        int kbase = kt * 16 + (lane >> 5) * 8;
        short8 v;
#pragma unroll
        for (int jj = 0; jj < 8; ++jj) {
            int k = kbase + jj;
            float f = (k < J.Kreal && col < HREAL) ? J.W[(size_t)k * HREAL + col] : 0.f;
            v[jj] = (short)f2bf(f);
        }
        J.dst[(size_t)(ct * J.KTfull + J.ktOff + kt) * 64 + lane] = v;
    } else {
        int id = (bid - PK_BASE) * 256 + tid;     // exact multiple (76800)
        u32 w = 0;
        if (cfg.mn[id]) w = 0x80000000u | ((u32)cfg.agp[id] << 16) | (u32)cfg.bgp[id];
        cfg.pk[id] = w;
    }
}

// ================= generic MFMA GEMM device core (32x32x16), W staged in LDS =================
// Block = 32*WAVES rows x 2 col-tiles; waves share the LDS W panel (one burst + barrier).
template<int KT, int KT1, int WAVES, bool RELU>
__device__ __forceinline__ void gemm_dev(
    int bx, int by, int tid,
    const __hip_bfloat16* __restrict__ A1,
    const __hip_bfloat16* __restrict__ A2,
    const short8* __restrict__ Wp,
    const float* __restrict__ bias0,
    __hip_bfloat16* __restrict__ out0,
    __hip_bfloat16* __restrict__ out1) {
    extern __shared__ short8 Wl[];             // [2*KT*64]
    const int lane = tid & 63;
    const int wv   = tid >> 6;
    const int m0   = bx * (32 * WAVES) + wv * 32;
    const int ct0  = by * 2;
    const int r1   = m0 + (lane & 31);
    const int koff = (lane >> 5) * 8;

    constexpr int S1  = KT1 * 16;
    constexpr int S2  = (KT - KT1) * 16;
    constexpr int CH  = (KT >= 10) ? 10 : KT;
    constexpr int NCH = KT / CH;
    constexpr int NW  = 2 * KT * 64;

    {
        const short8* wsrc = Wp + (size_t)ct0 * KT * 64;
#pragma unroll
        for (int i = 0; i < (NW + WAVES * 64 - 1) / (WAVES * 64); ++i) {
            const int idx = i * (WAVES * 64) + tid;
            if (NW % (WAVES * 64) == 0 || idx < NW) Wl[idx] = wsrc[idx];
        }
    }
    __syncthreads();

    f32x16 acc[2];
#pragma unroll
    for (int r = 0; r < 16; ++r) { acc[0][r] = 0.f; acc[1][r] = 0.f; }

    const short8* w0 = Wl + lane;
    const short8* w1 = Wl + KT * 64 + lane;

#pragma unroll
    for (int ch = 0; ch < NCH; ++ch) {
        short8 a[CH];
#pragma unroll
        for (int kt = 0; kt < CH; ++kt) {
            const int g = ch * CH + kt;
            if (g < KT1)
                a[kt] = *reinterpret_cast<const short8*>(A1 + (size_t)r1 * S1 + g * 16 + koff);
            else
                a[kt] = *reinterpret_cast<const short8*>(A2 + (size_t)r1 * S2 + (g - KT1) * 16 + koff);
        }
#pragma unroll
        for (int kt = 0; kt < CH; ++kt) {
            const int g = ch * CH + kt;
            acc[0] = __builtin_amdgcn_mfma_f32_32x32x16_bf16(a[kt], w0[g * 64], acc[0], 0, 0, 0);
            acc[1] = __builtin_amdgcn_mfma_f32_32x32x16_bf16(a[kt], w1[g * 64], acc[1], 0, 0, 0);
        }
    }

#pragma unroll
    for (int c = 0; c < 2; ++c) {
        const int ct = ct0 + c;
        const bool second = (ct >= NCT32);
        const int colb = second ? ct * 32 - HP : ct * 32;
        const int col = colb + (lane & 31);
        __hip_bfloat16* op = second ? out1 : out0;
        const float bb = (!second && bias0 && col < HREAL) ? bias0[col] : 0.f;
#pragma unroll
        for (int r = 0; r < 16; ++r) {
            const int row = m0 + (r & 3) + 8 * (r >> 2) + 4 * (lane >> 5);
            float v = acc[c][r] + bb;
            if (RELU) v = fmaxf(v, 0.f);
            op[(size_t)row * HP + col] = __float2bfloat16(v);
        }
    }
}

// ---- input GEMMs: fc1 (600 2-wave blocks) + bond dual (2500 2-wave blocks) in one launch ----
#define FC1_BLKS  (MA/64 * 5)          // 600
#define BOND_BLKS (MB/64 * 10)         // 2500
#define INPUT_LDS (2 * 6 * 64 * 16)    // 12288 B
__global__ __launch_bounds__(128)
void k_input_gemms(const __hip_bfloat16* __restrict__ A1b,
                   const __hip_bfloat16* __restrict__ bondb,
                   const short8* __restrict__ pW1,
                   const short8* __restrict__ pWbd,
                   const float* __restrict__ bgn,
                   __hip_bfloat16* __restrict__ af0,
                   __hip_bfloat16* __restrict__ bondgc,
                   __hip_bfloat16* __restrict__ bnb) {
    const int bid = blockIdx.x;
    if (bid < FC1_BLKS) {
        gemm_dev<6, 6, 2, true>(bid % (MA/64), bid / (MA/64), threadIdx.x,
                                A1b, A1b, pW1, nullptr, af0, nullptr);
    } else {
        const int b2 = bid - FC1_BLKS;
        gemm_dev<2, 2, 2, false>(b2 % (MB/64), b2 / (MB/64), threadIdx.x,
                                 bondb, bondb, pWbd, bgn, bondgc, bnb);
    }
}

// ---- bot GEMM: afn = relu([af|nei]@W_ga + b_ga), K=640, ONE ct per block ----
// 40KB W panel -> 4 blocks/CU, grid (60,10)=600 blocks (was 300x80KB at 2/CU, 59% fill).
#define BOT_LDS (40 * 64 * 16)         // 40960 B
__global__ __launch_bounds__(256)
void k_gemm_bot(const __hip_bfloat16* __restrict__ af,
                const __hip_bfloat16* __restrict__ neib,
                const short8* __restrict__ W,
                const float* __restrict__ b_ga,
                __hip_bfloat16* __restrict__ afn) {
    extern __shared__ short8 Wl[];             // [40*64]
    const int tid  = threadIdx.x;
    const int lane = tid & 63;
    const int wv   = tid >> 6;                 // 0..3
    const int m0   = blockIdx.x * 128 + wv * 32;
    const int ct   = blockIdx.y;
    const int r1   = m0 + (lane & 31);
    const int koff = (lane >> 5) * 8;
    constexpr int KT = 40, KT1 = 20;
    constexpr int S1 = KT1 * 16, S2 = (KT - KT1) * 16;

    {
        const short8* wsrc = W + (size_t)ct * KT * 64;
#pragma unroll
        for (int i = 0; i < (KT * 64) / 256; ++i) Wl[i * 256 + tid] = wsrc[i * 256 + tid];
    }
    __syncthreads();

    f32x16 acc;
#pragma unroll
    for (int r = 0; r < 16; ++r) acc[r] = 0.f;
    const short8* w0 = Wl + lane;

#pragma unroll
    for (int ch = 0; ch < 4; ++ch) {
        short8 a[10];
#pragma unroll
        for (int kt = 0; kt < 10; ++kt) {
            const int g = ch * 10 + kt;
            if (g < KT1)
                a[kt] = *reinterpret_cast<const short8*>(af + (size_t)r1 * S1 + g * 16 + koff);
            else
                a[kt] = *reinterpret_cast<const short8*>(neib + (size_t)r1 * S2 + (g - KT1) * 16 + koff);
        }
#pragma unroll
        for (int kt = 0; kt < 10; ++kt) {
            const int g = ch * 10 + kt;
            acc = __builtin_amdgcn_mfma_f32_32x32x16_bf16(a[kt], w0[g * 64], acc, 0, 0, 0);
        }
    }

    const int col = ct * 32 + (lane & 31);
    const float bb = (col < HREAL) ? b_ga[col] : 0.f;
#pragma unroll
    for (int r = 0; r < 16; ++r) {
        const int row = m0 + (r & 3) + 8 * (r >> 2) + 4 * (lane >> 5);
        afn[(size_t)row * HP + col] = __float2bfloat16(fmaxf(acc[r] + bb, 0.f));
    }
}

// ================= fused nu-GEMM + gather, one block per (batch, 32-col tile) =================
#define NUG_LDS (20*64*16 + 120*32*2 + 250*32*2 + 1200*4)   // 48960
__global__ __launch_bounds__(256)
void k_nu_gather(const __hip_bfloat16* __restrict__ af,
                 const short8* __restrict__ pWnei,
                 const u32* __restrict__ bondgc,   // [MB][160]
                 const u32* __restrict__ pk,
                 u32* __restrict__ nei) {          // [MA][160]
    extern __shared__ char smraw[];
    short8* WL = (short8*)smraw;                       // [20*64]
    u16*    TL = (u16*)(smraw + 20480);                // [120][32]
    u16*    BLh = (u16*)(smraw + 20480 + 7680);        // [250][32]
    u32*    PL = (u32*)(smraw + 20480 + 7680 + 16000); // [1200]
    u32*    BL = (u32*)BLh;                            // u32 view [250][16]
    const int b   = blockIdx.x;
    const int ct  = blockIdx.y;
    const int tid = threadIdx.x;

    {
        const short8* wsrc = pWnei + (size_t)ct * 20 * 64;
#pragma unroll
        for (int i = 0; i < 5; ++i) WL[i * 256 + tid] = wsrc[i * 256 + tid];
    }
    for (int i = tid; i < 2000; i += 256) {
        int r = i >> 3, w = i & 7;
        *reinterpret_cast<u32x2*>(&BL[r * 16 + 2 * w]) =
            *reinterpret_cast<const u32x2*>(bondgc + (size_t)(b * NBOND + r) * (HP / 2) + ct * 16 + 2 * w);
    }
    for (int i = tid; i < NATOM * NNB; i += 256) PL[i] = pk[b * NATOM * NNB + i];
    __syncthreads();

    {
        const int lane = tid & 63;
        const int wv   = tid >> 6;
        const int r1   = imin(wv * 32 + (lane & 31), NATOM - 1);
        const int koff = (lane >> 5) * 8;
        const __hip_bfloat16* arow = af + (size_t)(b * NATOM + r1) * HP + koff;
        f32x16 acc;
#pragma unroll
        for (int r = 0; r < 16; ++r) acc[r] = 0.f;
        const short8* w0 = WL + lane;
#pragma unroll
        for (int ch = 0; ch < 2; ++ch) {
            short8 a[10];
#pragma unroll
            for (int kt = 0; kt < 10; ++kt)
                a[kt] = *reinterpret_cast<const short8*>(arow + (ch * 10 + kt) * 16);
#pragma unroll
            for (int kt = 0; kt < 10; ++kt)
                acc = __builtin_amdgcn_mfma_f32_32x32x16_bf16(a[kt], w0[(ch * 10 + kt) * 64], acc, 0, 0, 0);
        }
        const int col = lane & 31;
#pragma unroll
        for (int r = 0; r < 16; ++r) {
            const int row = wv * 32 + (r & 3) + 8 * (r >> 2) + 4 * (lane >> 5);
            if (row < NATOM) TL[row * 32 + col] = f2bf(acc[r]);
        }
    }
    __syncthreads();

    for (int i = tid; i < NATOM * 16; i += 256) {
        const int row = i >> 4, cp = i & 15;
        float lo = 0.f, hi = 0.f;
#pragma unroll
        for (int j = 0; j < NNB; ++j) {
            const u32 w = PL[row * NNB + j];
            if ((int)w < 0) {
                const int a  = (w >> 16) & 0xff;
                const int bo = w & 0xffff;
                const u32 ta = *reinterpret_cast<const u32*>(&TL[a * 32 + 2 * cp]);
                const u32 tb = BL[bo * 16 + cp];
                lo += fmaxf(bflo(ta) + bflo(tb), 0.f);
                hi += fmaxf(bfhi(ta) + bfhi(tb), 0.f);
            }
        }
        nei[(size_t)(b * NATOM + row) * (HP / 2) + ct * 16 + cp] =
            (u32)f2bf(lo) | ((u32)f2bf(hi) << 16);
    }
}

// ================= fused final GEMM + product, one block per (batch, 32-col tile) =================
#define FIN_LDS (2*20*64*16 + 120*32*2 + 120*32*2 + 250*32*2 + 1200*4 + 120*4)  // 77600
__global__ __launch_bounds__(256)
void k_final_fused(const __hip_bfloat16* __restrict__ af,
                   const short8* __restrict__ pWfd,    // fc2 ct 0..9 | fc2a ct 10..19
                   const u32* __restrict__ bnb,        // [MB][160]
                   const u32* __restrict__ pk,
                   const int* __restrict__ maska,
                   float* __restrict__ out) {          // [MA][300]
    extern __shared__ char smraw[];
    short8* WL = (short8*)smraw;                              // [2*20*64]
    u16*    SL = (u16*)(smraw + 40960);                       // selfF [120][32]
    u16*    AL = (u16*)(smraw + 40960 + 7680);                // A2f   [120][32]
    u16*    BLh = (u16*)(smraw + 40960 + 2 * 7680);           // bnb   [250][32]
    u32*    PL = (u32*)(smraw + 40960 + 2 * 7680 + 16000);    // [1200]
    u32*    ML = PL + 1200;                                   // [120]
    u32*    BL = (u32*)BLh;
    const int b   = blockIdx.x;
    const int ct  = blockIdx.y;
    const int tid = threadIdx.x;

    {
        const short8* w2  = pWfd + (size_t)ct * 20 * 64;
        const short8* w2a = pWfd + (size_t)(NCT32 + ct) * 20 * 64;
#pragma unroll
        for (int i = 0; i < 5; ++i) {
            WL[i * 256 + tid]        = w2[i * 256 + tid];
            WL[1280 + i * 256 + tid] = w2a[i * 256 + tid];
        }
    }
    for (int i = tid; i < 2000; i += 256) {
        int r = i >> 3, w = i & 7;
        *reinterpret_cast<u32x2*>(&BL[r * 16 + 2 * w]) =
            *reinterpret_cast<const u32x2*>(bnb + (size_t)(b * NBOND + r) * (HP / 2) + ct * 16 + 2 * w);
    }
    for (int i = tid; i < NATOM * NNB; i += 256) PL[i] = pk[b * NATOM * NNB + i];
    for (int i = tid; i < NATOM; i += 256) ML[i] = (u32)(maska[b * NATOM + i] != 0);
    __syncthreads();

    {
        const int lane = tid & 63;
        const int wv   = tid >> 6;
        const int r1   = imin(wv * 32 + (lane & 31), NATOM - 1);
        const int koff = (lane >> 5) * 8;
        const __hip_bfloat16* arow = af + (size_t)(b * NATOM + r1) * HP + koff;
        f32x16 acc0, acc1;
#pragma unroll
        for (int r = 0; r < 16; ++r) { acc0[r] = 0.f; acc1[r] = 0.f; }
        const short8* w0 = WL + lane;
        const short8* w1 = WL + 1280 + lane;
#pragma unroll
        for (int ch = 0; ch < 2; ++ch) {
            short8 a[10];
#pragma unroll
            for (int kt = 0; kt < 10; ++kt)
                a[kt] = *reinterpret_cast<const short8*>(arow + (ch * 10 + kt) * 16);
#pragma unroll
            for (int kt = 0; kt < 10; ++kt) {
                acc0 = __builtin_amdgcn_mfma_f32_32x32x16_bf16(a[kt], w0[(ch * 10 + kt) * 64], acc0, 0, 0, 0);
                acc1 = __builtin_amdgcn_mfma_f32_32x32x16_bf16(a[kt], w1[(ch * 10 + kt) * 64], acc1, 0, 0, 0);
            }
        }
        const int col = lane & 31;
#pragma unroll
        for (int r = 0; r < 16; ++r) {
            const int row = wv * 32 + (r & 3) + 8 * (r >> 2) + 4 * (lane >> 5);
            if (row < NATOM) {
                SL[row * 32 + col] = f2bf(acc0[r]);
                AL[row * 32 + col] = f2bf(acc1[r]);
            }
        }
    }
    __syncthreads();

    for (int i = tid; i < NATOM * 16; i += 256) {
        const int row = i >> 4, cp = i & 15;
        const int c = ct * 32 + 2 * cp;
        if (c >= HREAL) continue;
        float lo = 0.f, hi = 0.f;
#pragma unroll
        for (int j = 0; j < NNB; ++j) {
            const u32 w = PL[row * NNB + j];
            if ((int)w < 0) {
                const int a  = (w >> 16) & 0xff;
                const int bo = w & 0xffff;
                const u32 va = *reinterpret_cast<const u32*>(&AL[a * 32 + 2 * cp]);
                const u32 vb = BL[bo * 16 + cp];
                lo += bflo(va) * bflo(vb);
                hi += bfhi(va) * bfhi(vb);
            }
        }
        float2 r2;
        r2.x = 0.f; r2.y = 0.f;
        if (ML[row]) {
            const u32 s = *reinterpret_cast<const u32*>(&SL[row * 32 + 2 * cp]);
            r2.x = bflo(s) * lo;
            r2.y = bfhi(s) * hi;
        }
        *reinterpret_cast<float2*>(out + (size_t)(b * NATOM + row) * HREAL + c) = r2;
    }
}

extern "C" void kernel_launch(void* const* d_in, const int* in_sizes, int n_in,
                              void* d_out, int out_size, void* d_ws, size_t ws_size,
                              hipStream_t stream) {
    const float* A1        = (const float*)d_in[0];
    const float* bond      = (const float*)d_in[1];
    const int*   ag        = (const int*)d_in[2];
    const int*   bg        = (const int*)d_in[3];
    const int*   maskn     = (const int*)d_in[6];
    const int*   maska     = (const int*)d_in[7];
    const float* W_fc1     = (const float*)d_in[8];
    const float* W_gc_nei  = (const float*)d_in[9];
    const float* b_gc_nei  = (const float*)d_in[10];
    const float* W_gc_atom = (const float*)d_in[11];
    const float* b_gc_atom = (const float*)d_in[12];
    const float* W_fc2a    = (const float*)d_in[13];
    const float* W_fc2b    = (const float*)d_in[14];
    const float* W_fc2     = (const float*)d_in[15];
    float* out = (float*)d_out;

    // ---- workspace carve-up ----
    char* p = (char*)d_ws;
    auto alloc = [&](size_t bytes) { char* r = p; p += (bytes + 63) & ~(size_t)63; return r; };
    __hip_bfloat16* A1b    = (__hip_bfloat16*)alloc((size_t)MA * 96 * 2);
    __hip_bfloat16* bondb  = (__hip_bfloat16*)alloc((size_t)MB * 32 * 2);
    __hip_bfloat16* af0    = (__hip_bfloat16*)alloc((size_t)MA * HP * 2);
    __hip_bfloat16* af1    = (__hip_bfloat16*)alloc((size_t)MA * HP * 2);
    __hip_bfloat16* neib   = (__hip_bfloat16*)alloc((size_t)MA * HP * 2);
    __hip_bfloat16* bondgc = (__hip_bfloat16*)alloc((size_t)MB * HP * 2);
    __hip_bfloat16* bnb    = (__hip_bfloat16*)alloc((size_t)MB * HP * 2);
    u32*            pk     = (u32*)alloc((size_t)MA * NNB * 4);         // packed nbr table
    short8* pW1  = (short8*)alloc((size_t)NCT32 * 6  * 64 * 16);        // fc1          K=96
    short8* pWnei= (short8*)alloc((size_t)NCT32 * 20 * 64 * 16);        // gc_nei[:H]   K=320
    short8* pWga = (short8*)alloc((size_t)NCT32 * 40 * 64 * 16);        // gc_atom cat  K=640
    short8* pWbd = (short8*)alloc((size_t)2 * NCT32 * 2 * 64 * 16);     // bond dual    K=32, 20 ct
    short8* pWfd = (short8*)alloc((size_t)2 * NCT32 * 20 * 64 * 16);    // fc2 | fc2a   K=320, 20 ct

    // ---- prep: convs + packs + pk in one launch ----
    Prep cfg;
    cfg.a1src = A1;   cfg.a1dst = A1b;
    cfg.bsrc  = bond; cfg.bdst  = bondb;
    cfg.mn = maskn; cfg.agp = ag; cfg.bgp = bg; cfg.pk = pk;
    //           W                                  dst                          Kreal  KT KTf off blk0
    cfg.j[0] = { W_fc1,                             pW1,                         AFDIM, 6,  6,  0,   0 };
    cfg.j[1] = { W_gc_nei,                          pWnei,                       HREAL, 20, 20, 0,  15 };
    cfg.j[2] = { W_gc_atom,                         pWga,                        HREAL, 20, 40, 0,  65 };
    cfg.j[3] = { W_gc_atom + (size_t)HREAL * HREAL, pWga,                        HREAL, 20, 40, 20, 115 };
    cfg.j[4] = { W_gc_nei + (size_t)HREAL * HREAL,  pWbd,                        BFDIM, 2,  2,  0, 165 };
    cfg.j[5] = { W_fc2b,                            pWbd + (size_t)NCT32*2*64,   BFDIM, 2,  2,  0, 170 };
    cfg.j[6] = { W_fc2,                             pWfd,                        HREAL, 20, 20, 0, 175 };
    cfg.j[7] = { W_fc2a,                            pWfd + (size_t)NCT32*20*64,  HREAL, 20, 20, 0, 225 };
    prep_all<<<dim3(PREP_BLKS), dim3(256), 0, stream>>>(cfg);

    // ---- opt-in LDS > 64 KB for the fused final kernel ----
    static int attr_done = 0;
    if (!attr_done) {
        hipFuncSetAttribute((const void*)k_final_fused, hipFuncAttributeMaxDynamicSharedMemorySize, FIN_LDS);
        attr_done = 1;
    }

    // ---- input GEMMs (fc1 + bond dual), W staged in LDS ----
    k_input_gemms<<<dim3(FC1_BLKS + BOND_BLKS), dim3(128), INPUT_LDS, stream>>>(
        A1b, bondb, pW1, pWbd, b_gc_nei, af0, bondgc, bnb);

    const dim3 gNUG(BATCH, NCT32);  // (64,10) fused nu+gather
    const dim3 gBOT(MA / 128, 10);  // (60,10) 1-ct K=640 bot, 4 blk/CU
    const dim3 t256(256);

    // ---- graph-conv iterations ----
    const __hip_bfloat16* af = af0;
    __hip_bfloat16* afn = af1;
    for (int it = 0; it < 2; ++it) {
        k_nu_gather<<<gNUG, t256, NUG_LDS, stream>>>(
            af, pWnei, (const u32*)bondgc, pk, (u32*)neib);
        k_gemm_bot<<<gBOT, t256, BOT_LDS, stream>>>(af, neib, pWga, b_gc_atom, afn);
        const __hip_bfloat16* t = afn; afn = (__hip_bfloat16*)af; af = t;
    }

    // ---- fused final layer ----
    k_final_fused<<<gNUG, t256, FIN_LDS, stream>>>(
        af, pWfd, (const u32*)bnb, pk, maska, out);
}